// Round 12
// baseline (3391.954 us; speedup 1.0000x reference)
//
#include <hip/hip_runtime.h>
#include <hip/hip_bf16.h>

#define BIG 1e30f

typedef __attribute__((ext_vector_type(8))) short short8;
typedef __attribute__((ext_vector_type(4))) float f32x4;

#define LGKM_FENCE() do { asm volatile("s_waitcnt lgkmcnt(0)" ::: "memory"); \
                          __builtin_amdgcn_sched_barrier(0); } while (0)
#define SCHED_FENCE() __builtin_amdgcn_sched_barrier(0)

__device__ __forceinline__ unsigned pk_bf16(float lo, float hi) {
    unsigned r;
    asm("v_cvt_pk_bf16_f32 %0, %1, %2" : "=v"(r) : "v"(lo), "v"(hi));
    return r;
}

__device__ __forceinline__ short8 make_frag(float4 a, float4 c) {
    union { unsigned u[4]; short8 s; } cv;
    cv.u[0] = pk_bf16(a.x, a.y);
    cv.u[1] = pk_bf16(a.z, a.w);
    cv.u[2] = pk_bf16(c.x, c.y);
    cv.u[3] = pk_bf16(c.z, c.w);
    return cv.s;
}

// shfl_up(v,1) via DPP wave_shr:1 (validated round 7, absmax 0.0).
__device__ __forceinline__ float dpp_shr1(float v) {
    int o = __builtin_amdgcn_update_dpp(__float_as_int(v), __float_as_int(v),
                                        0x138, 0xf, 0xf, false);
    return __int_as_float(o);
}

// =================== k_full: ROUND 9 VERBATIM (real result) ===================
__global__ __launch_bounds__(512, 1) void k_full(const float* __restrict__ x,
                                                 const float* __restrict__ y,
                                                 float* __restrict__ out)
{
    __shared__ float Dt[8][4096];
    __shared__ float y2s[512];
    __shared__ float rowA[3][8][65];

    const int b   = blockIdx.x;
    const int tid = threadIdx.x;
    const int w   = tid >> 6;
    const int l   = tid & 63;

    const float* xb = x + (size_t)b * 512 * 64;
    const float* yb = y + (size_t)b * 512 * 64;

    {
        const float4* yr = reinterpret_cast<const float4*>(yb + (size_t)tid * 64);
        float s = 0.f;
        #pragma unroll
        for (int q = 0; q < 16; ++q) {
            float4 v = yr[q];
            s += v.x*v.x + v.y*v.y + v.z*v.z + v.w*v.w;
        }
        y2s[tid] = s;
    }
    for (int i = tid; i < 3*8*65; i += 512) {
        ((float*)rowA)[i] = (i == 2*8*65) ? 0.0f : BIG;
    }

    const int lr = l & 15;
    const int lg = l >> 4;
    short8 afr[4][2];
    float  x2c[4][4];
    {
        float x2f[4];
        #pragma unroll
        for (int mi = 0; mi < 4; ++mi) {
            float part = 0.f;
            #pragma unroll
            for (int ks = 0; ks < 2; ++ks) {
                const float* rp = xb + (size_t)(w*64 + mi*16 + lr) * 64 + ks*32 + lg*8;
                float4 a0 = *reinterpret_cast<const float4*>(rp);
                float4 a1 = *reinterpret_cast<const float4*>(rp + 4);
                afr[mi][ks] = make_frag(a0, a1);
                part += a0.x*a0.x + a0.y*a0.y + a0.z*a0.z + a0.w*a0.w
                      + a1.x*a1.x + a1.y*a1.y + a1.z*a1.z + a1.w*a1.w;
            }
            part += __shfl_xor(part, 16);
            part += __shfl_xor(part, 32);
            x2f[mi] = part;
        }
        #pragma unroll
        for (int mi = 0; mi < 4; ++mi)
            #pragma unroll
            for (int i = 0; i < 4; ++i)
                x2c[mi][i] = __shfl(x2f[mi], lg*4 + i);
    }

    float* Dw = Dt[w];
    const int xr4 = (l & 7) << 2;
    float colreg = BIG;

    #pragma unroll 1
    for (int s = 0; s < 15; ++s) {
        __syncthreads();
        const int tj = s - w;
        if (tj < 0 || tj > 7) continue;
        const int j0 = tj * 64;

        f32x4 acc[4][4] = {};
        #pragma unroll
        for (int ni = 0; ni < 4; ++ni) {
            const float* rp = yb + (size_t)(j0 + ni*16 + lr) * 64 + lg*8;
            float4 b0 = *reinterpret_cast<const float4*>(rp);
            float4 b1 = *reinterpret_cast<const float4*>(rp + 4);
            float4 b2 = *reinterpret_cast<const float4*>(rp + 32);
            float4 b3 = *reinterpret_cast<const float4*>(rp + 36);
            short8 bf0 = make_frag(b0, b1);
            short8 bf1 = make_frag(b2, b3);
            #pragma unroll
            for (int mi = 0; mi < 4; ++mi) {
                acc[mi][ni] = __builtin_amdgcn_mfma_f32_16x16x32_bf16(afr[mi][0], bf0, acc[mi][ni], 0, 0, 0);
                acc[mi][ni] = __builtin_amdgcn_mfma_f32_16x16x32_bf16(afr[mi][1], bf1, acc[mi][ni], 0, 0, 0);
            }
        }
        #pragma unroll
        for (int ni = 0; ni < 4; ++ni) {
            float y2v = y2s[j0 + ni*16 + lr];
            #pragma unroll
            for (int mi = 0; mi < 4; ++mi) {
                #pragma unroll
                for (int i = 0; i < 4; ++i) {
                    int row = mi*16 + lg*4 + i;
                    int col = ni*16 + lr;
                    Dw[(row*64 + col) ^ ((row & 7) << 2)] = x2c[mi][i] + y2v - 2.0f * acc[mi][ni][i];
                }
            }
        }

        const float* rowR = rowA[(s + 2) % 3][tj];
        float*       rowW = rowA[s % 3][tj];

        if (tj == 0 && l == 0) rowW[0] = BIG;

        float r1 = colreg;
        float r2 = BIG;
        float saved = rowR[0];
        float colnext = BIG;

        auto issue_loads = [&](float (&dvb)[16], float (&rvb)[16], int k0) {
            #pragma unroll
            for (int u = 0; u < 16; ++u) {
                int kk = k0 + u;
                rvb[u] = rowR[1 + (kk & 63)];
                dvb[u] = Dw[(l << 6) + (((kk - l) & 63) ^ xr4)];
            }
        };
        auto compute16 = [&](float (&dvb)[16], float (&rvb)[16], int k0) {
            float rw[16];
            #pragma unroll
            for (int u = 0; u < 16; ++u) {
                int   kk   = k0 + u;
                int   c    = kk - l;
                float rowv = rvb[u];
                float dv   = dvb[u];
                float up   = dpp_shr1(r1);
                float dg   = dpp_shr1(r2);
                float pu   = (l == 0) ? rowv  : up;
                float pd   = (l == 0) ? saved : dg;
                float nv   = dv + fminf(fminf(pd, pu), r1);
                bool  act  = ((unsigned)c) < 64u;
                r2 = act ? r1 : r2;
                r1 = act ? nv : r1;
                colnext = (c == 63) ? nv : colnext;
                rw[u] = nv;
                saved = rowv;
            }
            if (l == 63) {
                #pragma unroll
                for (int u = 0; u < 16; ++u) {
                    int kk = k0 + u;
                    if ((unsigned)(kk - 63) < 64u) rowW[kk - 62] = rw[u];
                }
            }
        };

        float dvbA[16], rvbA[16], dvbB[16], rvbB[16];
        issue_loads(dvbA, rvbA, 0);
        LGKM_FENCE();
        #pragma unroll 1
        for (int k0 = 0; k0 < 128; k0 += 32) {
            issue_loads(dvbB, rvbB, k0 + 16);
            SCHED_FENCE();
            compute16(dvbA, rvbA, k0);
            LGKM_FENCE();
            if (k0 < 96) issue_loads(dvbA, rvbA, k0 + 32);
            SCHED_FENCE();
            compute16(dvbB, rvbB, k0 + 16);
            LGKM_FENCE();
        }
        colreg = colnext;
        if (l == 63 && tj < 7) rowA[(s + 1) % 3][tj + 1][0] = colnext;
    }

    if (w == 7 && l == 63) out[b] = colreg;
}

// ============== k_dtw8: DTW machinery only (garbage D), x8 reps ==============
__global__ __launch_bounds__(512, 1) void k_dtw8(float* __restrict__ ws, unsigned wsn)
{
    __shared__ float Dt[8][4096];
    __shared__ float rowA[3][8][65];

    const int b   = blockIdx.x;
    const int tid = threadIdx.x;
    const int w   = tid >> 6;
    const int l   = tid & 63;

    for (int i = tid; i < 3*8*65; i += 512) {
        ((float*)rowA)[i] = (i == 2*8*65) ? 0.0f : BIG;
    }
    // touch Dt so its 128KB stays allocated (same occupancy as k_full)
    Dt[w][l] = (float)tid;
    __syncthreads();

    float* Dw = Dt[w];
    const int xr4 = (l & 7) << 2;
    float colreg = BIG;

    #pragma unroll 1
    for (int rep = 0; rep < 8; ++rep) {
        #pragma unroll 1
        for (int s = 0; s < 15; ++s) {
            __syncthreads();
            const int tj = s - w;
            if (tj < 0 || tj > 7) continue;

            const float* rowR = rowA[(s + 2) % 3][tj];
            float*       rowW = rowA[s % 3][tj];

            if (tj == 0 && l == 0) rowW[0] = BIG;

            float r1 = colreg;
            float r2 = BIG;
            float saved = rowR[0];
            float colnext = BIG;

            auto issue_loads = [&](float (&dvb)[16], float (&rvb)[16], int k0) {
                #pragma unroll
                for (int u = 0; u < 16; ++u) {
                    int kk = k0 + u;
                    rvb[u] = rowR[1 + (kk & 63)];
                    dvb[u] = Dw[(l << 6) + (((kk - l) & 63) ^ xr4)];
                }
            };
            auto compute16 = [&](float (&dvb)[16], float (&rvb)[16], int k0) {
                float rw[16];
                #pragma unroll
                for (int u = 0; u < 16; ++u) {
                    int   kk   = k0 + u;
                    int   c    = kk - l;
                    float rowv = rvb[u];
                    float dv   = dvb[u];
                    float up   = dpp_shr1(r1);
                    float dg   = dpp_shr1(r2);
                    float pu   = (l == 0) ? rowv  : up;
                    float pd   = (l == 0) ? saved : dg;
                    float nv   = dv + fminf(fminf(pd, pu), r1);
                    bool  act  = ((unsigned)c) < 64u;
                    r2 = act ? r1 : r2;
                    r1 = act ? nv : r1;
                    colnext = (c == 63) ? nv : colnext;
                    rw[u] = nv;
                    saved = rowv;
                }
                if (l == 63) {
                    #pragma unroll
                    for (int u = 0; u < 16; ++u) {
                        int kk = k0 + u;
                        if ((unsigned)(kk - 63) < 64u) rowW[kk - 62] = rw[u];
                    }
                }
            };

            float dvbA[16], rvbA[16], dvbB[16], rvbB[16];
            issue_loads(dvbA, rvbA, 0);
            LGKM_FENCE();
            #pragma unroll 1
            for (int k0 = 0; k0 < 128; k0 += 32) {
                issue_loads(dvbB, rvbB, k0 + 16);
                SCHED_FENCE();
                compute16(dvbA, rvbA, k0);
                LGKM_FENCE();
                if (k0 < 96) issue_loads(dvbA, rvbA, k0 + 32);
                SCHED_FENCE();
                compute16(dvbB, rvbB, k0 + 16);
                LGKM_FENCE();
            }
            colreg = colnext;
            if (l == 63 && tj < 7) rowA[(s + 1) % 3][tj + 1][0] = colnext;
        }
    }

    unsigned idx = 128u + (unsigned)b;
    if (w == 7 && l == 63 && (idx + 1) * 4 <= wsn) ws[idx] = colreg;
}

// ========= k_chain32: pure VALU/DPP chain, zero LDS in loop, x32 reps =========
__global__ __launch_bounds__(512, 1) void k_chain32(float* __restrict__ ws, unsigned wsn)
{
    __shared__ float Dt[8][4096];
    __shared__ float rowA[3][8][65];

    const int b   = blockIdx.x;
    const int tid = threadIdx.x;
    const int w   = tid >> 6;
    const int l   = tid & 63;

    // touch shared so LDS footprint (and occupancy) matches k_full
    Dt[w][l] = (float)tid;
    ((float*)rowA)[tid & 1023] = (float)l;
    __syncthreads();

    float colreg = BIG;

    #pragma unroll 1
    for (int rep = 0; rep < 32; ++rep) {
        #pragma unroll 1
        for (int s = 0; s < 15; ++s) {
            __syncthreads();
            const int tj = s - w;
            if (tj < 0 || tj > 7) continue;

            float base = (float)(s + rep);
            float r1 = colreg;
            float r2 = BIG;
            float saved = base;
            float colnext = BIG;

            #pragma unroll 1
            for (int k0 = 0; k0 < 128; k0 += 16) {
                #pragma unroll
                for (int u = 0; u < 16; ++u) {
                    int   kk   = k0 + u;
                    int   c    = kk - l;
                    float rowv = base + (float)u * 0.5f;     // stand-in, off-chain
                    float dv   = base + (float)u * 0.25f;    // stand-in, off-chain
                    float up   = dpp_shr1(r1);
                    float dg   = dpp_shr1(r2);
                    float pu   = (l == 0) ? rowv  : up;
                    float pd   = (l == 0) ? saved : dg;
                    float nv   = dv + fminf(fminf(pd, pu), r1);
                    bool  act  = ((unsigned)c) < 64u;
                    r2 = act ? r1 : r2;
                    r1 = act ? nv : r1;
                    colnext = (c == 63) ? nv : colnext;
                    saved = rowv;
                }
            }
            colreg = colnext;
        }
    }

    unsigned idx = 256u + (unsigned)b;
    if (w == 7 && l == 63 && (idx + 1) * 4 <= wsn) ws[idx] = colreg;
}

extern "C" void kernel_launch(void* const* d_in, const int* in_sizes, int n_in,
                              void* d_out, int out_size, void* d_ws, size_t ws_size,
                              hipStream_t stream) {
    (void)in_sizes; (void)n_in; (void)out_size;
    const float* x = (const float*)d_in[0];
    const float* y = (const float*)d_in[1];
    float* out = (float*)d_out;
    float* ws  = (float*)d_ws;
    unsigned wsn = (unsigned)(ws_size > 0xFFFFFFFFu ? 0xFFFFFFFFu : ws_size);

    k_full<<<128, 512, 0, stream>>>(x, y, out);        // real result (~185 us)
    k_dtw8<<<128, 512, 0, stream>>>(ws, wsn);          // 8 x M2 (DTW machinery)
    k_chain32<<<128, 512, 0, stream>>>(ws, wsn);       // 32 x M3 (pure chain)
}

// Round 13
// 225.865 us; speedup vs baseline: 15.0176x; 15.0176x over previous
//
#include <hip/hip_runtime.h>
#include <hip/hip_bf16.h>

#define BIG 1e30f

typedef __attribute__((ext_vector_type(8))) short short8;
typedef __attribute__((ext_vector_type(4))) float f32x4;

#define LGKM_FENCE() do { asm volatile("s_waitcnt lgkmcnt(0)" ::: "memory"); \
                          __builtin_amdgcn_sched_barrier(0); } while (0)
#define SCHED_FENCE() __builtin_amdgcn_sched_barrier(0)

__device__ __forceinline__ unsigned pk_bf16(float lo, float hi) {
    unsigned r;
    asm("v_cvt_pk_bf16_f32 %0, %1, %2" : "=v"(r) : "v"(lo), "v"(hi));
    return r;
}

__device__ __forceinline__ short8 make_frag(float4 a, float4 c) {
    union { unsigned u[4]; short8 s; } cv;
    cv.u[0] = pk_bf16(a.x, a.y);
    cv.u[1] = pk_bf16(a.z, a.w);
    cv.u[2] = pk_bf16(c.x, c.y);
    cv.u[3] = pk_bf16(c.z, c.w);
    return cv.s;
}

// shfl_up(v,1) via DPP wave_shr:1 (validated round 7, absmax 0.0).
__device__ __forceinline__ float dpp_shr1(float v) {
    int o = __builtin_amdgcn_update_dpp(__float_as_int(v), __float_as_int(v),
                                        0x138, 0xf, 0xf, false);
    return __int_as_float(o);
}

// ROUND 13: producer/consumer wave split. 16 waves per block (1024 thr).
// Waves 0-7 = consumers: run the r9-verified DTW loop on stage s.
// Waves 8-15 = producers: MFMA-GEMM stage s+1's D tile into the other half
// of a double-buffered bf16-packed LDS store (D2[buf][panel][r2*64+c]; u32
// packs rows {2*r2, 2*r2+1} at col c). One barrier per stage; parity
// alternation guarantees no producer/consumer overlap on the same buffer.
// Ablation (r12): chain 68us + LDS 60us + GEMM 57us; this hides the GEMM.
__global__ __launch_bounds__(1024, 1) void dtw_fused(const float* __restrict__ x,
                                                     const float* __restrict__ y,
                                                     float* __restrict__ out)
{
    __shared__ unsigned D2[2][8][2048];   // 128 KB: [buf][panel][r2*64 + col]
    __shared__ float y2s[512];
    __shared__ float rowA[3][8][65];      // [parity][tj][0]=corner, [1+j]=bottom row

    const int b   = blockIdx.x;
    const int tid = threadIdx.x;
    const int w   = tid >> 6;             // 0..15
    const int l   = tid & 63;
    const bool prod = (w >= 8);
    const int  p    = w & 7;              // producer panel / consumer panel

    const float* xb = x + (size_t)b * 512 * 64;
    const float* yb = y + (size_t)b * 512 * 64;

    const int lr = l & 15;
    const int lg = l >> 4;

    short8 afr[4][2];
    float  x2c[4][4];

    // ---------------- prologue ----------------
    if (!prod) {
        // consumers: init rowA (512 threads cover 1560 floats)
        for (int i = tid; i < 3*8*65; i += 512)
            ((float*)rowA)[i] = (i == 2*8*65) ? 0.0f : BIG;
    } else {
        // producers: y2s (tid-512 -> row), then afr + x2 for panel p
        {
            int r = tid - 512;
            const float4* yr = reinterpret_cast<const float4*>(yb + (size_t)r * 64);
            float ssum = 0.f;
            #pragma unroll
            for (int q = 0; q < 16; ++q) {
                float4 v = yr[q];
                ssum += v.x*v.x + v.y*v.y + v.z*v.z + v.w*v.w;
            }
            y2s[r] = ssum;
        }
        float x2f[4];
        #pragma unroll
        for (int mi = 0; mi < 4; ++mi) {
            float part = 0.f;
            #pragma unroll
            for (int ks = 0; ks < 2; ++ks) {
                const float* rp = xb + (size_t)(p*64 + mi*16 + lr) * 64 + ks*32 + lg*8;
                float4 a0 = *reinterpret_cast<const float4*>(rp);
                float4 a1 = *reinterpret_cast<const float4*>(rp + 4);
                afr[mi][ks] = make_frag(a0, a1);
                part += a0.x*a0.x + a0.y*a0.y + a0.z*a0.z + a0.w*a0.w
                      + a1.x*a1.x + a1.y*a1.y + a1.z*a1.z + a1.w*a1.w;
            }
            part += __shfl_xor(part, 16);
            part += __shfl_xor(part, 32);
            x2f[mi] = part;
        }
        #pragma unroll
        for (int mi = 0; mi < 4; ++mi)
            #pragma unroll
            for (int i = 0; i < 4; ++i)
                x2c[mi][i] = __shfl(x2f[mi], lg*4 + i);
    }
    __syncthreads();   // y2s/rowA ready

    // producer: compute tile (p, tjp) -> packed bf16 into D2w
    auto gemm_tile = [&](int tjp, unsigned* D2w) {
        const int j0 = tjp * 64;
        f32x4 acc[4][4] = {};
        #pragma unroll
        for (int ni = 0; ni < 4; ++ni) {
            const float* rp = yb + (size_t)(j0 + ni*16 + lr) * 64 + lg*8;
            float4 b0 = *reinterpret_cast<const float4*>(rp);
            float4 b1 = *reinterpret_cast<const float4*>(rp + 4);
            float4 b2 = *reinterpret_cast<const float4*>(rp + 32);
            float4 b3 = *reinterpret_cast<const float4*>(rp + 36);
            short8 bf0 = make_frag(b0, b1);
            short8 bf1 = make_frag(b2, b3);
            #pragma unroll
            for (int mi = 0; mi < 4; ++mi) {
                acc[mi][ni] = __builtin_amdgcn_mfma_f32_16x16x32_bf16(afr[mi][0], bf0, acc[mi][ni], 0, 0, 0);
                acc[mi][ni] = __builtin_amdgcn_mfma_f32_16x16x32_bf16(afr[mi][1], bf1, acc[mi][ni], 0, 0, 0);
            }
        }
        #pragma unroll
        for (int ni = 0; ni < 4; ++ni) {
            float y2v = y2s[j0 + ni*16 + lr];
            #pragma unroll
            for (int mi = 0; mi < 4; ++mi) {
                #pragma unroll
                for (int ip = 0; ip < 2; ++ip) {
                    int pr2 = mi*8 + lg*2 + ip;           // rows {2*pr2, 2*pr2+1}
                    float d0 = x2c[mi][2*ip]   + y2v - 2.0f * acc[mi][ni][2*ip];
                    float d1 = x2c[mi][2*ip+1] + y2v - 2.0f * acc[mi][ni][2*ip+1];
                    D2w[pr2*64 + ni*16 + lr] = pk_bf16(d0, d1);
                }
            }
        }
    };

    // pre-produce tile (0,0) into buf 0
    if (prod && p == 0) gemm_tile(0, D2[0][0]);
    __syncthreads();

    float colreg = BIG;
    const unsigned dshift = (l & 1) ? 0u : 16u;   // odd row = hi half, even = lo
    const int      dbase  = (l >> 1) * 64;

    #pragma unroll 1
    for (int s = 0; s < 15; ++s) {
        if (prod) {
            int tjp = s + 1 - p;
            if (tjp >= 0 && tjp <= 7 && s < 14)
                gemm_tile(tjp, D2[(s + 1) & 1][p]);
        } else {
            const int tj = s - w;
            if (tj >= 0 && tj <= 7) {
                const unsigned* D2w = D2[s & 1][w];
                const float* rowR = rowA[(s + 2) % 3][tj];
                float*       rowW = rowA[s % 3][tj];

                if (tj == 0 && l == 0) rowW[0] = BIG;

                float r1 = colreg;
                float r2 = BIG;
                float saved = rowR[0];
                float colnext = BIG;

                auto issue_loads = [&](unsigned (&dvb)[16], float (&rvb)[16], int k0) {
                    #pragma unroll
                    for (int u = 0; u < 16; ++u) {
                        int kk = k0 + u;
                        rvb[u] = rowR[1 + (kk & 63)];
                        dvb[u] = D2w[dbase + ((kk - l) & 63)];
                    }
                };
                auto compute16 = [&](unsigned (&dvb)[16], float (&rvb)[16], int k0) {
                    float rw[16];
                    #pragma unroll
                    for (int u = 0; u < 16; ++u) {
                        int   kk   = k0 + u;
                        int   c    = kk - l;
                        float rowv = rvb[u];
                        float dv   = __uint_as_float((dvb[u] << dshift) & 0xFFFF0000u);
                        float up   = dpp_shr1(r1);
                        float dg   = dpp_shr1(r2);
                        float pu   = (l == 0) ? rowv  : up;
                        float pd   = (l == 0) ? saved : dg;
                        float nv   = dv + fminf(fminf(pd, pu), r1);
                        bool  act  = ((unsigned)c) < 64u;
                        r2 = act ? r1 : r2;
                        r1 = act ? nv : r1;
                        colnext = (c == 63) ? nv : colnext;
                        rw[u] = nv;
                        saved = rowv;
                    }
                    if (l == 63) {
                        #pragma unroll
                        for (int u = 0; u < 16; ++u) {
                            int kk = k0 + u;
                            if ((unsigned)(kk - 63) < 64u) rowW[kk - 62] = rw[u];
                        }
                    }
                };

                unsigned dvbA[16], dvbB[16];
                float    rvbA[16], rvbB[16];
                issue_loads(dvbA, rvbA, 0);
                LGKM_FENCE();
                #pragma unroll 1
                for (int k0 = 0; k0 < 128; k0 += 32) {
                    issue_loads(dvbB, rvbB, k0 + 16);
                    SCHED_FENCE();
                    compute16(dvbA, rvbA, k0);
                    LGKM_FENCE();
                    if (k0 < 96) issue_loads(dvbA, rvbA, k0 + 32);
                    SCHED_FENCE();
                    compute16(dvbB, rvbB, k0 + 16);
                    LGKM_FENCE();
                }
                colreg = colnext;
                if (l == 63 && tj < 7) rowA[(s + 1) % 3][tj + 1][0] = colnext;
            }
        }
        __syncthreads();   // all 16 waves, every stage: buffers flip safely
    }

    if (w == 7 && l == 63) out[b] = colreg;   // consumer wave 7: R[511][511]
}

extern "C" void kernel_launch(void* const* d_in, const int* in_sizes, int n_in,
                              void* d_out, int out_size, void* d_ws, size_t ws_size,
                              hipStream_t stream) {
    (void)in_sizes; (void)n_in; (void)d_ws; (void)ws_size; (void)out_size;
    const float* x = (const float*)d_in[0];
    const float* y = (const float*)d_in[1];
    float* out = (float*)d_out;
    dtw_fused<<<128, 1024, 0, stream>>>(x, y, out);
}